// Round 3
// 542.457 us; speedup vs baseline: 1.1709x; 1.1709x over previous
//
#include <hip/hip_runtime.h>
#include <math.h>

#define BATCH 8
#define N 2048
#define D 256
#define K_INST 512
#define K_REL 32
#define PAIRS_PER_B (K_INST * K_REL)   // 16384

// ---------------------------------------------------------------------------
// fp32 -> fp16 hi/lo split (lo pre-scaled by 2^11 so it stays in fp16 normal
// range). x = h + l/2048 + r with |r| <= 2^-24 |x|  (fp32-epsilon level).
// Uses native _Float16 casts (RNE) — no hip_fp16.h dependency.
// ---------------------------------------------------------------------------
__device__ __forceinline__ unsigned short f2h_u(float f) {
  _Float16 h = (_Float16)f;                       // RNE
  return __builtin_bit_cast(unsigned short, h);
}
__device__ __forceinline__ float h2f_u(unsigned short u) {
  return (float)__builtin_bit_cast(_Float16, u);  // exact
}

// Kernel 0: q,k fp32 -> qh/ql/kh/kl fp16 arrays (one pass, vectorized).
__global__ __launch_bounds__(256)
void split_f16(const float* __restrict__ q, const float* __restrict__ k,
               unsigned short* __restrict__ qh, unsigned short* __restrict__ ql,
               unsigned short* __restrict__ kh, unsigned short* __restrict__ kl) {
  const int E4 = BATCH * N * D / 4;   // float4 chunks per tensor
  for (int i = blockIdx.x * blockDim.x + threadIdx.x; i < 2 * E4;
       i += gridDim.x * blockDim.x) {
    const bool isK = i >= E4;
    const int j = isK ? (i - E4) : i;
    const float4 v = ((const float4*)(isK ? k : q))[j];
    ushort4 h, l;
    h.x = f2h_u(v.x); h.y = f2h_u(v.y); h.z = f2h_u(v.z); h.w = f2h_u(v.w);
    l.x = f2h_u(2048.0f * (v.x - h2f_u(h.x)));
    l.y = f2h_u(2048.0f * (v.y - h2f_u(h.y)));
    l.z = f2h_u(2048.0f * (v.z - h2f_u(h.z)));
    l.w = f2h_u(2048.0f * (v.w - h2f_u(h.w)));
    ((ushort4*)(isK ? kh : qh))[j] = h;
    ((ushort4*)(isK ? kl : ql))[j] = l;
  }
}

// ---------------------------------------------------------------------------
// Kernel 1: scores = q @ k^T via fp16-split MFMA (3 terms, 2 acc banks).
//   accH += ah*bh                     (scale 1)
//   accC += ah*bl' + al'*bh          (scale 2048, lo pre-scaled)
//   score = accH + accC / 2048
// 128x128 tile, BK=32, 256 threads (4 waves), per-wave 4x4 frags of
// mfma_f32_16x16x32_f16.
// Staging: global_load_lds width=16, linear LDS dest, inverse-swizzled
// global source + swizzled ds_read (rule: both-sides-or-neither).
// ---------------------------------------------------------------------------
#define TM 128
#define TN 128
#define TK 32

typedef _Float16 f16x8 __attribute__((ext_vector_type(8)));  // 8 f16 = 4 VGPRs
typedef float f32x4 __attribute__((ext_vector_type(4)));

__device__ __forceinline__ void load_lds16(const void* g, void* l) {
  __builtin_amdgcn_global_load_lds(
      (const __attribute__((address_space(1))) void*)g,
      (__attribute__((address_space(3))) void*)l, 16, 0, 0);
}

__global__ __launch_bounds__(256)
void gemm_qkT_mfma(const unsigned short* __restrict__ qh,
                   const unsigned short* __restrict__ ql,
                   const unsigned short* __restrict__ kh,
                   const unsigned short* __restrict__ kl,
                   float* __restrict__ out) {
  const int bz = blockIdx.z;
  const int row0 = blockIdx.y * TM;
  const int col0 = blockIdx.x * TN;
  const size_t tb = (size_t)bz * N * D;

  // 4 tiles of [128 rows][32 k] fp16, linear (global_load_lds writes
  // base + lane*16 contiguously). 32 KiB total.
  __shared__ unsigned short Ah[TM * TK], Al[TM * TK], Bh[TM * TK], Bl[TM * TK];

  const int tid = threadIdx.x;
  const int lane = tid & 63;
  const int w = tid >> 6;          // wave 0..3
  const int wr = w >> 1, wc = w & 1;
  const int fr = lane & 15;        // row/col within a 16x16 fragment
  const int g = lane >> 4;         // k-group 0..3 (8 f16 each)
  // XOR swizzle of the 16B k-chunk within a 64B row: chunk' = chunk ^ (row&3).
  // For fragment reads row&3 == lane&3 (frag bases are multiples of 16).
  const int slot8 = ((g ^ (lane & 3)) << 3);  // swizzled k-offset (ushorts)

  // staging decode: wave covers LDS bytes b = (2w+i)*1024 + lane*16 per tile
  int r_st[2], k_st[2];
#pragma unroll
  for (int i = 0; i < 2; i++) {
    const int b = ((w * 2 + i) << 10) + lane * 16;
    const int r = b >> 6;           // tile row 0..127
    const int s = (b >> 4) & 3;     // 16B slot within the row
    r_st[i] = r;
    k_st[i] = (s ^ (r & 3)) * 8;    // inverse-swizzled global k-chunk (ushorts)
  }

  f32x4 accH[4][4], accC[4][4];
#pragma unroll
  for (int m = 0; m < 4; m++)
#pragma unroll
    for (int n = 0; n < 4; n++) {
      accH[m][n] = (f32x4){0.f, 0.f, 0.f, 0.f};
      accC[m][n] = (f32x4){0.f, 0.f, 0.f, 0.f};
    }

  for (int kt = 0; kt < D; kt += TK) {
    __syncthreads();               // all waves done reading previous tile
#pragma unroll
    for (int i = 0; i < 2; i++) {
      const size_t aoff = tb + (size_t)(row0 + r_st[i]) * D + kt + k_st[i];
      const size_t boff = tb + (size_t)(col0 + r_st[i]) * D + kt + k_st[i];
      unsigned short* const la = &Ah[(w * 2 + i) * 512];   // wave-uniform dest
      unsigned short* const lA = &Al[(w * 2 + i) * 512];
      unsigned short* const lb = &Bh[(w * 2 + i) * 512];
      unsigned short* const lB = &Bl[(w * 2 + i) * 512];
      load_lds16(qh + aoff, la);
      load_lds16(ql + aoff, lA);
      load_lds16(kh + boff, lb);
      load_lds16(kl + boff, lB);
    }
    __syncthreads();               // barrier drains vmcnt -> tiles ready

    f16x8 ah[4], al[4];
#pragma unroll
    for (int m = 0; m < 4; m++) {
      const int idx = (wr * 64 + m * 16 + fr) * TK + slot8;
      ah[m] = *(const f16x8*)&Ah[idx];
      al[m] = *(const f16x8*)&Al[idx];
    }
#pragma unroll
    for (int n = 0; n < 4; n++) {
      const int idx = (wc * 64 + n * 16 + fr) * TK + slot8;
      const f16x8 bhf = *(const f16x8*)&Bh[idx];
      const f16x8 blf = *(const f16x8*)&Bl[idx];
#pragma unroll
      for (int m = 0; m < 4; m++) {
        accH[m][n] = __builtin_amdgcn_mfma_f32_16x16x32_f16(ah[m], bhf, accH[m][n], 0, 0, 0);
        accC[m][n] = __builtin_amdgcn_mfma_f32_16x16x32_f16(ah[m], blf, accC[m][n], 0, 0, 0);
        accC[m][n] = __builtin_amdgcn_mfma_f32_16x16x32_f16(al[m], bhf, accC[m][n], 0, 0, 0);
      }
    }
  }

  // C/D layout: col = lane&15, row = (lane>>4)*4 + reg (m89-verified)
  float* O = out + (size_t)bz * N * N;
  const float inv2048 = 1.0f / 2048.0f;
#pragma unroll
  for (int m = 0; m < 4; m++) {
#pragma unroll
    for (int r4 = 0; r4 < 4; r4++) {
      float* orow =
          &O[(size_t)(row0 + wr * 64 + m * 16 + g * 4 + r4) * N + col0 + wc * 64 + fr];
#pragma unroll
      for (int n = 0; n < 4; n++)
        orow[n * 16] = fmaf(accC[m][n][r4], inv2048, accH[m][n][r4]);
    }
  }
}

// ---------------------------------------------------------------------------
// Kernel 2: per-row max, sum(exp), and softmax diagonal value.
// One 256-thread block per row (B*N = 16384 rows).
// ---------------------------------------------------------------------------
__global__ __launch_bounds__(256)
void row_stats(const float* __restrict__ scores, float* __restrict__ m_out,
               float* __restrict__ s_out, float* __restrict__ diag_out) {
  const int row = blockIdx.x;              // b*N + i
  const float* srow = scores + (size_t)row * N;
  const float4* r4 = (const float4*)srow;
  const int t = threadIdx.x;
  const int lane = t & 63, wid = t >> 6;
  float4 v0 = r4[t];
  float4 v1 = r4[t + 256];
  float mx = fmaxf(fmaxf(fmaxf(v0.x, v0.y), fmaxf(v0.z, v0.w)),
                   fmaxf(fmaxf(v1.x, v1.y), fmaxf(v1.z, v1.w)));
  __shared__ float redm[4], reds[4], bc[1];
#pragma unroll
  for (int o = 32; o > 0; o >>= 1) mx = fmaxf(mx, __shfl_down(mx, o));
  if (lane == 0) redm[wid] = mx;
  __syncthreads();
  if (t == 0) bc[0] = fmaxf(fmaxf(redm[0], redm[1]), fmaxf(redm[2], redm[3]));
  __syncthreads();
  const float m = bc[0];
  float s = expf(v0.x - m) + expf(v0.y - m) + expf(v0.z - m) + expf(v0.w - m)
          + expf(v1.x - m) + expf(v1.y - m) + expf(v1.z - m) + expf(v1.w - m);
#pragma unroll
  for (int o = 32; o > 0; o >>= 1) s += __shfl_down(s, o);
  if (lane == 0) reds[wid] = s;
  __syncthreads();
  if (t == 0) {
    float S = reds[0] + reds[1] + reds[2] + reds[3];
    int i = row & (N - 1);
    float sii = srow[i];
    m_out[row] = m;
    s_out[row] = S;
    diag_out[row] = expf(sii - m) / S;
  }
}

// ---------------------------------------------------------------------------
// Kernel 3: per-batch top-512 of diag (jax.lax.top_k tie-break: lower index
// first), then output the selected indices sorted ascending.
// One 256-thread block per batch. Bitonic sort of 2048 (val desc, idx asc).
// ---------------------------------------------------------------------------
__global__ __launch_bounds__(256)
void topk_inst(const float* __restrict__ diag, int* __restrict__ inst) {
  const int b = blockIdx.x;
  __shared__ float v[2048];
  __shared__ int id[2048];
  __shared__ int sel[K_INST];
  const int tid = threadIdx.x;
  for (int e = tid; e < 2048; e += 256) { v[e] = diag[b * N + e]; id[e] = e; }
  __syncthreads();
  for (int k = 2; k <= 2048; k <<= 1) {
    for (int j = k >> 1; j > 0; j >>= 1) {
      for (int p = tid; p < 1024; p += 256) {
        int i = 2 * p - (p & (j - 1));
        int ixj = i | j;
        float va = v[i], vb = v[ixj];
        int ia = id[i], ib = id[ixj];
        bool a_first = (va > vb) || (va == vb && ia < ib);  // descending order
        bool up = ((i & k) == 0);
        if (up != a_first) { v[i] = vb; v[ixj] = va; id[i] = ib; id[ixj] = ia; }
      }
      __syncthreads();
    }
  }
  for (int e = tid; e < K_INST; e += 256) sel[e] = id[e];
  __syncthreads();
  // sort the 512 selected indices ascending (bitonic, 256 pairs = 1/thread)
  for (int k = 2; k <= K_INST; k <<= 1) {
    for (int j = k >> 1; j > 0; j >>= 1) {
      int p = tid;
      int i = 2 * p - (p & (j - 1));
      int ixj = i | j;
      int a = sel[i], c = sel[ixj];
      bool a_first = a < c;           // ascending
      bool up = ((i & k) == 0);
      if (up != a_first) { sel[i] = c; sel[ixj] = a; }
      __syncthreads();
    }
  }
  for (int e = tid; e < K_INST; e += 256) inst[b * K_INST + e] = sel[e];
}

// ---------------------------------------------------------------------------
// Kernel 4: rel matrix row -> top-32 columns (tie-break lower col), columns
// sorted ascending; emit soi (as floats) and int (subj,obj) pairs for k5.
// One 256-thread block per rel row (B*512 = 4096 blocks).
// ---------------------------------------------------------------------------
__global__ __launch_bounds__(256)
void rel_topk(const float* __restrict__ scores, const float* __restrict__ m_arr,
              const float* __restrict__ s_arr, const int* __restrict__ inst,
              float* __restrict__ soi_out, int* __restrict__ pairs) {
  const int blk = blockIdx.x;
  const int b = blk >> 9;
  const int r = blk & 511;
  __shared__ float v[K_INST];
  __shared__ int c[K_INST];
  __shared__ int selc[K_REL];
  __shared__ int sortedc[K_REL];
  const int tid = threadIdx.x;
  const int subj = inst[b * K_INST + r];
  const int rowg = b * N + subj;
  const float m = m_arr[rowg];
  const float S = s_arr[rowg];
  const float* srow = scores + (size_t)rowg * N;
  for (int e = tid; e < K_INST; e += 256) {
    int col = inst[b * K_INST + e];
    v[e] = (e == r) ? 1e9f : expf(srow[col] - m) / S;  // prob value, like ref
    c[e] = e;
  }
  __syncthreads();
  for (int k = 2; k <= K_INST; k <<= 1) {
    for (int j = k >> 1; j > 0; j >>= 1) {
      int p = tid;
      int i = 2 * p - (p & (j - 1));
      int ixj = i | j;
      float va = v[i], vb = v[ixj];
      int ia = c[i], ib = c[ixj];
      bool a_first = (va > vb) || (va == vb && ia < ib);  // descending
      bool up = ((i & k) == 0);
      if (up != a_first) { v[i] = vb; v[ixj] = va; c[i] = ib; c[ixj] = ia; }
      __syncthreads();
    }
  }
  if (tid < K_REL) selc[tid] = c[tid];
  __syncthreads();
  if (tid < K_REL) {
    int myc = selc[tid];
    int rank = 0;
#pragma unroll
    for (int p2 = 0; p2 < K_REL; p2++) rank += (selc[p2] < myc);
    sortedc[rank] = myc;
  }
  __syncthreads();
  if (tid < K_REL) {
    int cc = sortedc[tid];
    int obj = inst[b * K_INST + cc];
    size_t pidx = (size_t)b * PAIRS_PER_B + (size_t)r * K_REL + tid;
    soi_out[pidx * 3 + 0] = (float)b;
    soi_out[pidx * 3 + 1] = (float)subj;
    soi_out[pidx * 3 + 2] = (float)obj;
    pairs[pidx * 2 + 0] = subj;
    pairs[pidx * 2 + 1] = obj;
  }
}

// ---------------------------------------------------------------------------
// Kernel 5: rel_e = layernorm(q[subj] + q[obj]) over D=256, no affine.
// One 256-thread block per pair (131072 blocks).
// ---------------------------------------------------------------------------
__global__ __launch_bounds__(256)
void rel_embed(const float* __restrict__ q, const int* __restrict__ pairs,
               float* __restrict__ out) {
  const size_t p = blockIdx.x;
  const int b = (int)(p >> 14);
  const int subj = pairs[p * 2], obj = pairs[p * 2 + 1];
  const float* qs = q + ((size_t)b * N + subj) * D;
  const float* qo = q + ((size_t)b * N + obj) * D;
  const int t = threadIdx.x;
  const int lane = t & 63, wid = t >> 6;
  __shared__ float red[4];
  __shared__ float bc[2];
  float e = qs[t] + qo[t];
  float s = e;
#pragma unroll
  for (int o = 32; o > 0; o >>= 1) s += __shfl_down(s, o);
  if (lane == 0) red[wid] = s;
  __syncthreads();
  if (t == 0) bc[0] = (red[0] + red[1] + red[2] + red[3]) * (1.0f / D);
  __syncthreads();
  float mu = bc[0];
  float dv = e - mu;
  float s2 = dv * dv;
#pragma unroll
  for (int o = 32; o > 0; o >>= 1) s2 += __shfl_down(s2, o);
  if (lane == 0) red[wid] = s2;   // safe: all reads of red happened before prev barrier
  __syncthreads();
  if (t == 0) bc[1] = (red[0] + red[1] + red[2] + red[3]) * (1.0f / D);
  __syncthreads();
  float var = bc[1];
  out[p * D + t] = dv * rsqrtf(var + 1e-5f);
}

// ---------------------------------------------------------------------------
extern "C" void kernel_launch(void* const* d_in, const int* in_sizes, int n_in,
                              void* d_out, int out_size, void* d_ws, size_t ws_size,
                              hipStream_t stream) {
  const float* q = (const float*)d_in[0];
  const float* k = (const float*)d_in[1];
  float* out = (float*)d_out;

  // Output layout (flat fp32, return order): scores1, soi, rel_e
  float* scores = out;                                   // 8*2048*2048
  float* soi = out + (size_t)BATCH * N * N;              // 8*16384*3
  float* rele = soi + (size_t)BATCH * PAIRS_PER_B * 3;   // 8*16384*256

  // Workspace layout
  float* m_arr = (float*)d_ws;                 // 16384 f
  float* s_arr = m_arr + BATCH * N;            // 16384 f
  float* diag = s_arr + BATCH * N;             // 16384 f
  int* inst = (int*)(diag + BATCH * N);        // 4096 i
  int* pairs = inst + BATCH * K_INST;          // 262144 i

  // fp16 hi/lo stash (33.6 MB) lives at the head of the rel_e output region
  // (134 MB). It is consumed by the GEMM and fully overwritten by rel_embed
  // at the end; the stream is serial so this is safe.
  unsigned short* qh = (unsigned short*)rele;
  unsigned short* ql = qh + (size_t)BATCH * N * D;
  unsigned short* kh = ql + (size_t)BATCH * N * D;
  unsigned short* kl = kh + (size_t)BATCH * N * D;

  split_f16<<<4096, 256, 0, stream>>>(q, k, qh, ql, kh, kl);
  gemm_qkT_mfma<<<dim3(N / TN, N / TM, BATCH), 256, 0, stream>>>(qh, ql, kh, kl, scores);
  row_stats<<<BATCH * N, 256, 0, stream>>>(scores, m_arr, s_arr, diag);
  topk_inst<<<BATCH, 256, 0, stream>>>(diag, inst);
  rel_topk<<<BATCH * K_INST, 256, 0, stream>>>(scores, m_arr, s_arr, inst, soi, pairs);
  rel_embed<<<BATCH * PAIRS_PER_B, 256, 0, stream>>>(q, pairs, rele);
}

// Round 4
// 423.462 us; speedup vs baseline: 1.5000x; 1.2810x over previous
//
#include <hip/hip_runtime.h>
#include <math.h>

#define BATCH 8
#define N 2048
#define D 256
#define K_INST 512
#define K_REL 32
#define PAIRS_PER_B (K_INST * K_REL)   // 16384

// ---------------------------------------------------------------------------
// fp32 -> fp16 hi/lo split (lo pre-scaled by 2^11 so it stays in fp16 normal
// range). x = h + l/2048 + r with |r| <= 2^-24 |x|  (fp32-epsilon level).
// Uses native _Float16 casts (RNE) — no hip_fp16.h dependency.
// ---------------------------------------------------------------------------
__device__ __forceinline__ unsigned short f2h_u(float f) {
  _Float16 h = (_Float16)f;                       // RNE
  return __builtin_bit_cast(unsigned short, h);
}
__device__ __forceinline__ float h2f_u(unsigned short u) {
  return (float)__builtin_bit_cast(_Float16, u);  // exact
}

// Kernel 0: q,k fp32 -> qh/ql/kh/kl fp16 arrays (one pass, vectorized).
__global__ __launch_bounds__(256)
void split_f16(const float* __restrict__ q, const float* __restrict__ k,
               unsigned short* __restrict__ qh, unsigned short* __restrict__ ql,
               unsigned short* __restrict__ kh, unsigned short* __restrict__ kl) {
  const int E4 = BATCH * N * D / 4;   // float4 chunks per tensor
  for (int i = blockIdx.x * blockDim.x + threadIdx.x; i < 2 * E4;
       i += gridDim.x * blockDim.x) {
    const bool isK = i >= E4;
    const int j = isK ? (i - E4) : i;
    const float4 v = ((const float4*)(isK ? k : q))[j];
    ushort4 h, l;
    h.x = f2h_u(v.x); h.y = f2h_u(v.y); h.z = f2h_u(v.z); h.w = f2h_u(v.w);
    l.x = f2h_u(2048.0f * (v.x - h2f_u(h.x)));
    l.y = f2h_u(2048.0f * (v.y - h2f_u(h.y)));
    l.z = f2h_u(2048.0f * (v.z - h2f_u(h.z)));
    l.w = f2h_u(2048.0f * (v.w - h2f_u(h.w)));
    ((ushort4*)(isK ? kh : qh))[j] = h;
    ((ushort4*)(isK ? kl : ql))[j] = l;
  }
}

// ---------------------------------------------------------------------------
// Kernel 1: scores = q @ k^T via fp16-split MFMA (3 terms, SINGLE acc bank).
// Per fragment per K-step:
//   t   = mfma(ah, bl, 0); t = mfma(al, bh, t)   (cross terms, scale 2048)
//   acc = mfma(ah, bh, acc); acc += t * 2^-11
// Single bank frees ~64 VGPRs vs dual-bank -> 3 waves/SIMD (m97 operating pt).
// 128x128 tile, BK=32, 256 threads (4 waves), per-wave 4x4 frags of
// mfma_f32_16x16x32_f16.
// Staging: global_load_lds width=16, linear LDS dest, inverse-swizzled
// global source + swizzled ds_read (rule: both-sides-or-neither).
// ---------------------------------------------------------------------------
#define TM 128
#define TN 128
#define TK 32

typedef _Float16 f16x8 __attribute__((ext_vector_type(8)));  // 8 f16 = 4 VGPRs
typedef float f32x4 __attribute__((ext_vector_type(4)));

__device__ __forceinline__ void load_lds16(const void* g, void* l) {
  __builtin_amdgcn_global_load_lds(
      (const __attribute__((address_space(1))) void*)g,
      (__attribute__((address_space(3))) void*)l, 16, 0, 0);
}

__global__ __launch_bounds__(256, 3)
void gemm_qkT_mfma(const unsigned short* __restrict__ qh,
                   const unsigned short* __restrict__ ql,
                   const unsigned short* __restrict__ kh,
                   const unsigned short* __restrict__ kl,
                   float* __restrict__ out) {
  const int bz = blockIdx.z;
  const int row0 = blockIdx.y * TM;
  const int col0 = blockIdx.x * TN;
  const size_t tb = (size_t)bz * N * D;

  // 4 tiles of [128 rows][32 k] fp16, linear (global_load_lds writes
  // base + lane*16 contiguously). 32 KiB total.
  __shared__ unsigned short Ah[TM * TK], Al[TM * TK], Bh[TM * TK], Bl[TM * TK];

  const int tid = threadIdx.x;
  const int lane = tid & 63;
  const int w = tid >> 6;          // wave 0..3
  const int wr = w >> 1, wc = w & 1;
  const int fr = lane & 15;        // row/col within a 16x16 fragment
  const int g = lane >> 4;         // k-group 0..3 (8 f16 each)
  // XOR swizzle of the 16B k-chunk within a 64B row: chunk' = chunk ^ (row&3).
  // For fragment reads row&3 == lane&3 (frag bases are multiples of 16).
  const int slot8 = ((g ^ (lane & 3)) << 3);  // swizzled k-offset (ushorts)

  // staging decode: wave covers LDS bytes b = (2w+i)*1024 + lane*16 per tile
  int r_st[2], k_st[2];
#pragma unroll
  for (int i = 0; i < 2; i++) {
    const int b = ((w * 2 + i) << 10) + lane * 16;
    const int r = b >> 6;           // tile row 0..127
    const int s = (b >> 4) & 3;     // 16B slot within the row
    r_st[i] = r;
    k_st[i] = (s ^ (r & 3)) * 8;    // inverse-swizzled global k-chunk (ushorts)
  }

  f32x4 acc[4][4];
#pragma unroll
  for (int m = 0; m < 4; m++)
#pragma unroll
    for (int n = 0; n < 4; n++) acc[m][n] = (f32x4){0.f, 0.f, 0.f, 0.f};
  const f32x4 zero4 = (f32x4){0.f, 0.f, 0.f, 0.f};
  const float inv2048 = 1.0f / 2048.0f;

  for (int kt = 0; kt < D; kt += TK) {
    __syncthreads();               // all waves done reading previous tile
#pragma unroll
    for (int i = 0; i < 2; i++) {
      const size_t aoff = tb + (size_t)(row0 + r_st[i]) * D + kt + k_st[i];
      const size_t boff = tb + (size_t)(col0 + r_st[i]) * D + kt + k_st[i];
      unsigned short* const la = &Ah[(w * 2 + i) * 512];   // wave-uniform dest
      unsigned short* const lA = &Al[(w * 2 + i) * 512];
      unsigned short* const lb = &Bh[(w * 2 + i) * 512];
      unsigned short* const lB = &Bl[(w * 2 + i) * 512];
      load_lds16(qh + aoff, la);
      load_lds16(ql + aoff, lA);
      load_lds16(kh + boff, lb);
      load_lds16(kl + boff, lB);
    }
    __syncthreads();               // barrier drains vmcnt -> tiles ready

    f16x8 ah[4], al[4];
#pragma unroll
    for (int m = 0; m < 4; m++) {
      const int idx = (wr * 64 + m * 16 + fr) * TK + slot8;
      ah[m] = *(const f16x8*)&Ah[idx];
      al[m] = *(const f16x8*)&Al[idx];
    }
#pragma unroll
    for (int n = 0; n < 4; n++) {
      const int idx = (wc * 64 + n * 16 + fr) * TK + slot8;
      const f16x8 bhf = *(const f16x8*)&Bh[idx];
      const f16x8 blf = *(const f16x8*)&Bl[idx];
#pragma unroll
      for (int m = 0; m < 4; m++) {
        f32x4 t = __builtin_amdgcn_mfma_f32_16x16x32_f16(ah[m], blf, zero4, 0, 0, 0);
        t = __builtin_amdgcn_mfma_f32_16x16x32_f16(al[m], bhf, t, 0, 0, 0);
        acc[m][n] = __builtin_amdgcn_mfma_f32_16x16x32_f16(ah[m], bhf, acc[m][n], 0, 0, 0);
        acc[m][n] += t * inv2048;   // 4 fmac on the VALU pipe (overlaps MFMA)
      }
    }
  }

  // C/D layout: col = lane&15, row = (lane>>4)*4 + reg (m89-verified)
  float* O = out + (size_t)bz * N * N;
#pragma unroll
  for (int m = 0; m < 4; m++) {
#pragma unroll
    for (int r4 = 0; r4 < 4; r4++) {
      float* orow =
          &O[(size_t)(row0 + wr * 64 + m * 16 + g * 4 + r4) * N + col0 + wc * 64 + fr];
#pragma unroll
      for (int n = 0; n < 4; n++) orow[n * 16] = acc[m][n][r4];
    }
  }
}

// ---------------------------------------------------------------------------
// Kernel 2: per-row max, sum(exp), and softmax diagonal value.
// One 256-thread block per row (B*N = 16384 rows).
// ---------------------------------------------------------------------------
__global__ __launch_bounds__(256)
void row_stats(const float* __restrict__ scores, float* __restrict__ m_out,
               float* __restrict__ s_out, float* __restrict__ diag_out) {
  const int row = blockIdx.x;              // b*N + i
  const float* srow = scores + (size_t)row * N;
  const float4* r4 = (const float4*)srow;
  const int t = threadIdx.x;
  const int lane = t & 63, wid = t >> 6;
  float4 v0 = r4[t];
  float4 v1 = r4[t + 256];
  float mx = fmaxf(fmaxf(fmaxf(v0.x, v0.y), fmaxf(v0.z, v0.w)),
                   fmaxf(fmaxf(v1.x, v1.y), fmaxf(v1.z, v1.w)));
  __shared__ float redm[4], reds[4], bc[1];
#pragma unroll
  for (int o = 32; o > 0; o >>= 1) mx = fmaxf(mx, __shfl_down(mx, o));
  if (lane == 0) redm[wid] = mx;
  __syncthreads();
  if (t == 0) bc[0] = fmaxf(fmaxf(redm[0], redm[1]), fmaxf(redm[2], redm[3]));
  __syncthreads();
  const float m = bc[0];
  float s = expf(v0.x - m) + expf(v0.y - m) + expf(v0.z - m) + expf(v0.w - m)
          + expf(v1.x - m) + expf(v1.y - m) + expf(v1.z - m) + expf(v1.w - m);
#pragma unroll
  for (int o = 32; o > 0; o >>= 1) s += __shfl_down(s, o);
  if (lane == 0) reds[wid] = s;
  __syncthreads();
  if (t == 0) {
    float S = reds[0] + reds[1] + reds[2] + reds[3];
    int i = row & (N - 1);
    float sii = srow[i];
    m_out[row] = m;
    s_out[row] = S;
    diag_out[row] = expf(sii - m) / S;
  }
}

// ---------------------------------------------------------------------------
// Kernel 3: per-batch top-512 of diag (jax.lax.top_k tie-break: lower index
// first), then output the selected indices sorted ascending.
// One 1024-thread block per batch (1 compare-pair per thread per stage).
// ---------------------------------------------------------------------------
__global__ __launch_bounds__(1024)
void topk_inst(const float* __restrict__ diag, int* __restrict__ inst) {
  const int b = blockIdx.x;
  __shared__ float v[2048];
  __shared__ int id[2048];
  __shared__ int sel[K_INST];
  const int tid = threadIdx.x;
  for (int e = tid; e < 2048; e += 1024) { v[e] = diag[b * N + e]; id[e] = e; }
  __syncthreads();
  for (int k = 2; k <= 2048; k <<= 1) {
    for (int j = k >> 1; j > 0; j >>= 1) {
      const int p = tid;               // 1024 pairs, one per thread
      int i = 2 * p - (p & (j - 1));
      int ixj = i | j;
      float va = v[i], vb = v[ixj];
      int ia = id[i], ib = id[ixj];
      bool a_first = (va > vb) || (va == vb && ia < ib);  // descending order
      bool up = ((i & k) == 0);
      if (up != a_first) { v[i] = vb; v[ixj] = va; id[i] = ib; id[ixj] = ia; }
      __syncthreads();
    }
  }
  if (tid < K_INST) sel[tid] = id[tid];
  __syncthreads();
  // sort the 512 selected indices ascending (bitonic, 256 pairs)
  for (int k = 2; k <= K_INST; k <<= 1) {
    for (int j = k >> 1; j > 0; j >>= 1) {
      if (tid < 256) {
        int p = tid;
        int i = 2 * p - (p & (j - 1));
        int ixj = i | j;
        int a = sel[i], c = sel[ixj];
        bool a_first = a < c;           // ascending
        bool up = ((i & k) == 0);
        if (up != a_first) { sel[i] = c; sel[ixj] = a; }
      }
      __syncthreads();
    }
  }
  if (tid < K_INST) inst[b * K_INST + tid] = sel[tid];
}

// ---------------------------------------------------------------------------
// Kernel 4: rel matrix row -> top-32 columns (tie-break lower col), columns
// sorted ascending; emit soi (as floats) and int (subj,obj) pairs for k5.
// One 256-thread block per rel row (B*512 = 4096 blocks).
// ---------------------------------------------------------------------------
__global__ __launch_bounds__(256)
void rel_topk(const float* __restrict__ scores, const float* __restrict__ m_arr,
              const float* __restrict__ s_arr, const int* __restrict__ inst,
              float* __restrict__ soi_out, int* __restrict__ pairs) {
  const int blk = blockIdx.x;
  const int b = blk >> 9;
  const int r = blk & 511;
  __shared__ float v[K_INST];
  __shared__ int c[K_INST];
  __shared__ int selc[K_REL];
  __shared__ int sortedc[K_REL];
  const int tid = threadIdx.x;
  const int subj = inst[b * K_INST + r];
  const int rowg = b * N + subj;
  const float m = m_arr[rowg];
  const float S = s_arr[rowg];
  const float* srow = scores + (size_t)rowg * N;
  for (int e = tid; e < K_INST; e += 256) {
    int col = inst[b * K_INST + e];
    v[e] = (e == r) ? 1e9f : expf(srow[col] - m) / S;  // prob value, like ref
    c[e] = e;
  }
  __syncthreads();
  for (int k = 2; k <= K_INST; k <<= 1) {
    for (int j = k >> 1; j > 0; j >>= 1) {
      int p = tid;
      int i = 2 * p - (p & (j - 1));
      int ixj = i | j;
      float va = v[i], vb = v[ixj];
      int ia = c[i], ib = c[ixj];
      bool a_first = (va > vb) || (va == vb && ia < ib);  // descending
      bool up = ((i & k) == 0);
      if (up != a_first) { v[i] = vb; v[ixj] = va; c[i] = ib; c[ixj] = ia; }
      __syncthreads();
    }
  }
  if (tid < K_REL) selc[tid] = c[tid];
  __syncthreads();
  if (tid < K_REL) {
    int myc = selc[tid];
    int rank = 0;
#pragma unroll
    for (int p2 = 0; p2 < K_REL; p2++) rank += (selc[p2] < myc);
    sortedc[rank] = myc;
  }
  __syncthreads();
  if (tid < K_REL) {
    int cc = sortedc[tid];
    int obj = inst[b * K_INST + cc];
    size_t pidx = (size_t)b * PAIRS_PER_B + (size_t)r * K_REL + tid;
    soi_out[pidx * 3 + 0] = (float)b;
    soi_out[pidx * 3 + 1] = (float)subj;
    soi_out[pidx * 3 + 2] = (float)obj;
    pairs[pidx * 2 + 0] = subj;
    pairs[pidx * 2 + 1] = obj;
  }
}

// ---------------------------------------------------------------------------
// Kernel 5: rel_e = layernorm(q[subj] + q[obj]) over D=256, no affine.
// One wave per pair, float4 loads, pure shuffle reduce (no LDS, no barriers).
// 4 pairs per 256-thread block -> 32768 blocks.
// ---------------------------------------------------------------------------
__global__ __launch_bounds__(256)
void rel_embed(const float* __restrict__ q, const int* __restrict__ pairs,
               float* __restrict__ out) {
  const size_t p = (size_t)blockIdx.x * 4 + (threadIdx.x >> 6);
  const int lane = threadIdx.x & 63;
  const int b = (int)(p >> 14);
  const int subj = pairs[p * 2], obj = pairs[p * 2 + 1];
  const float* qs = q + ((size_t)b * N + subj) * D;
  const float* qo = q + ((size_t)b * N + obj) * D;
  const float4 a = *(const float4*)(qs + lane * 4);
  const float4 c = *(const float4*)(qo + lane * 4);
  float4 e = make_float4(a.x + c.x, a.y + c.y, a.z + c.z, a.w + c.w);
  float s = e.x + e.y + e.z + e.w;
#pragma unroll
  for (int o = 32; o > 0; o >>= 1) s += __shfl_down(s, o);
  const float mu = __shfl(s, 0) * (1.0f / D);
  float4 dv = make_float4(e.x - mu, e.y - mu, e.z - mu, e.w - mu);
  float s2 = dv.x * dv.x + dv.y * dv.y + dv.z * dv.z + dv.w * dv.w;
#pragma unroll
  for (int o = 32; o > 0; o >>= 1) s2 += __shfl_down(s2, o);
  const float var = __shfl(s2, 0) * (1.0f / D);
  const float r = rsqrtf(var + 1e-5f);
  *(float4*)(out + p * D + lane * 4) =
      make_float4(dv.x * r, dv.y * r, dv.z * r, dv.w * r);
}

// ---------------------------------------------------------------------------
extern "C" void kernel_launch(void* const* d_in, const int* in_sizes, int n_in,
                              void* d_out, int out_size, void* d_ws, size_t ws_size,
                              hipStream_t stream) {
  const float* q = (const float*)d_in[0];
  const float* k = (const float*)d_in[1];
  float* out = (float*)d_out;

  // Output layout (flat fp32, return order): scores1, soi, rel_e
  float* scores = out;                                   // 8*2048*2048
  float* soi = out + (size_t)BATCH * N * N;              // 8*16384*3
  float* rele = soi + (size_t)BATCH * PAIRS_PER_B * 3;   // 8*16384*256

  // Workspace layout
  float* m_arr = (float*)d_ws;                 // 16384 f
  float* s_arr = m_arr + BATCH * N;            // 16384 f
  float* diag = s_arr + BATCH * N;             // 16384 f
  int* inst = (int*)(diag + BATCH * N);        // 4096 i
  int* pairs = inst + BATCH * K_INST;          // 262144 i

  // fp16 hi/lo stash (33.6 MB) lives at the head of the rel_e output region
  // (134 MB). It is consumed by the GEMM and fully overwritten by rel_embed
  // at the end; the stream is serial so this is safe.
  unsigned short* qh = (unsigned short*)rele;
  unsigned short* ql = qh + (size_t)BATCH * N * D;
  unsigned short* kh = ql + (size_t)BATCH * N * D;
  unsigned short* kl = kh + (size_t)BATCH * N * D;

  split_f16<<<4096, 256, 0, stream>>>(q, k, qh, ql, kh, kl);
  gemm_qkT_mfma<<<dim3(N / TN, N / TM, BATCH), 256, 0, stream>>>(qh, ql, kh, kl, scores);
  row_stats<<<BATCH * N, 256, 0, stream>>>(scores, m_arr, s_arr, diag);
  topk_inst<<<BATCH, 1024, 0, stream>>>(diag, inst);
  rel_topk<<<BATCH * K_INST, 256, 0, stream>>>(scores, m_arr, s_arr, inst, soi, pairs);
  rel_embed<<<BATCH * PAIRS_PER_B / 4, 256, 0, stream>>>(q, pairs, rele);
}

// Round 5
// 420.914 us; speedup vs baseline: 1.5091x; 1.0061x over previous
//
#include <hip/hip_runtime.h>
#include <math.h>

#define BATCH 8
#define N 2048
#define D 256
#define K_INST 512
#define K_REL 32
#define PAIRS_PER_B (K_INST * K_REL)   // 16384

// ---------------------------------------------------------------------------
// fp32 -> fp16 hi/lo split (lo pre-scaled by 2^11; hi also stored pre-scaled
// by 2^11 in a third array so the GEMM can accumulate all 3 terms into one
// fp32 bank at scale 2048 with ZERO loop VALU).
//   x = h + l/2048 + r,  |r| <= 2^-24 |x|
//   hs = 2048*h (exact in fp16: max |2048*q| ~ 11k < 65504)
// ---------------------------------------------------------------------------
__device__ __forceinline__ unsigned short f2h_u(float f) {
  _Float16 h = (_Float16)f;                       // RNE
  return __builtin_bit_cast(unsigned short, h);
}
__device__ __forceinline__ float h2f_u(unsigned short u) {
  return (float)__builtin_bit_cast(_Float16, u);  // exact
}

// Kernel 0: q -> qhs/qh/ql ; k -> kh/kl (one pass, vectorized).
__global__ __launch_bounds__(256)
void split_f16(const float* __restrict__ q, const float* __restrict__ k,
               unsigned short* __restrict__ qhs, unsigned short* __restrict__ qh,
               unsigned short* __restrict__ ql, unsigned short* __restrict__ kh,
               unsigned short* __restrict__ kl) {
  const int E4 = BATCH * N * D / 4;   // float4 chunks per tensor
  for (int i = blockIdx.x * blockDim.x + threadIdx.x; i < 2 * E4;
       i += gridDim.x * blockDim.x) {
    const bool isK = i >= E4;
    const int j = isK ? (i - E4) : i;
    const float4 v = ((const float4*)(isK ? k : q))[j];
    ushort4 h, l;
    h.x = f2h_u(v.x); h.y = f2h_u(v.y); h.z = f2h_u(v.z); h.w = f2h_u(v.w);
    l.x = f2h_u(2048.0f * (v.x - h2f_u(h.x)));
    l.y = f2h_u(2048.0f * (v.y - h2f_u(h.y)));
    l.z = f2h_u(2048.0f * (v.z - h2f_u(h.z)));
    l.w = f2h_u(2048.0f * (v.w - h2f_u(h.w)));
    if (isK) {
      ((ushort4*)kh)[j] = h;
      ((ushort4*)kl)[j] = l;
    } else {
      ushort4 hs;
      hs.x = f2h_u(2048.0f * h2f_u(h.x));   // exact power-of-2 scale
      hs.y = f2h_u(2048.0f * h2f_u(h.y));
      hs.z = f2h_u(2048.0f * h2f_u(h.z));
      hs.w = f2h_u(2048.0f * h2f_u(h.w));
      ((ushort4*)qhs)[j] = hs;
      ((ushort4*)qh)[j] = h;
      ((ushort4*)ql)[j] = l;
    }
  }
}

// ---------------------------------------------------------------------------
// Kernel 1: scores = q @ k^T via fp16-split MFMA, single acc bank at
// scale 2048:
//   acc' = mfma(ahs,bh) ; acc' = mfma(ah,bl) ; acc' = mfma(al,bh)
//   score = acc' * 2^-11   (epilogue only — no loop VALU)
// 128x128 tile, BK=32, 256 threads (4 waves), per-wave 4x4 frags of
// mfma_f32_16x16x32_f16. 5 staged tiles (40 KiB LDS).
// Staging: global_load_lds width=16, linear LDS dest, inverse-swizzled
// global source + swizzled ds_read (rule: both-sides-or-neither).
// ---------------------------------------------------------------------------
#define TM 128
#define TN 128
#define TK 32

typedef _Float16 f16x8 __attribute__((ext_vector_type(8)));  // 8 f16 = 4 VGPRs
typedef float f32x4 __attribute__((ext_vector_type(4)));

__device__ __forceinline__ void load_lds16(const void* g, void* l) {
  __builtin_amdgcn_global_load_lds(
      (const __attribute__((address_space(1))) void*)g,
      (__attribute__((address_space(3))) void*)l, 16, 0, 0);
}

__global__ __launch_bounds__(256, 3)
void gemm_qkT_mfma(const unsigned short* __restrict__ qhs,
                   const unsigned short* __restrict__ qh,
                   const unsigned short* __restrict__ ql,
                   const unsigned short* __restrict__ kh,
                   const unsigned short* __restrict__ kl,
                   float* __restrict__ out) {
  const int bz = blockIdx.z;
  const int row0 = blockIdx.y * TM;
  const int col0 = blockIdx.x * TN;
  const size_t tb = (size_t)bz * N * D;

  // 5 tiles of [128 rows][32 k] fp16, linear layout. 40 KiB total.
  __shared__ unsigned short Ahs[TM * TK], Ah[TM * TK], Al[TM * TK],
                            Bh[TM * TK], Bl[TM * TK];

  const int tid = threadIdx.x;
  const int lane = tid & 63;
  const int w = tid >> 6;          // wave 0..3
  const int wr = w >> 1, wc = w & 1;
  const int fr = lane & 15;        // row/col within a 16x16 fragment
  const int g = lane >> 4;         // k-group 0..3 (8 f16 each)
  // XOR swizzle of the 16B k-chunk within a 64B row: chunk' = chunk ^ (row&3).
  // For fragment reads row&3 == lane&3 (frag bases are multiples of 16).
  const int slot8 = ((g ^ (lane & 3)) << 3);  // swizzled k-offset (ushorts)

  // staging decode: wave covers LDS bytes b = (2w+i)*1024 + lane*16 per tile
  int r_st[2], k_st[2];
#pragma unroll
  for (int i = 0; i < 2; i++) {
    const int b = ((w * 2 + i) << 10) + lane * 16;
    const int r = b >> 6;           // tile row 0..127
    const int s = (b >> 4) & 3;     // 16B slot within the row
    r_st[i] = r;
    k_st[i] = (s ^ (r & 3)) * 8;    // inverse-swizzled global k-chunk (ushorts)
  }

  f32x4 acc[4][4];
#pragma unroll
  for (int m = 0; m < 4; m++)
#pragma unroll
    for (int n = 0; n < 4; n++) acc[m][n] = (f32x4){0.f, 0.f, 0.f, 0.f};

  for (int kt = 0; kt < D; kt += TK) {
    __syncthreads();               // all waves done reading previous tile
#pragma unroll
    for (int i = 0; i < 2; i++) {
      const size_t aoff = tb + (size_t)(row0 + r_st[i]) * D + kt + k_st[i];
      const size_t boff = tb + (size_t)(col0 + r_st[i]) * D + kt + k_st[i];
      const int ldsoff = (w * 2 + i) * 512;        // wave-uniform dest
      load_lds16(qhs + aoff, &Ahs[ldsoff]);
      load_lds16(qh  + aoff, &Ah[ldsoff]);
      load_lds16(ql  + aoff, &Al[ldsoff]);
      load_lds16(kh  + boff, &Bh[ldsoff]);
      load_lds16(kl  + boff, &Bl[ldsoff]);
    }
    __syncthreads();               // barrier drains vmcnt -> tiles ready

    f16x8 ahs[4], ah[4], al[4];
#pragma unroll
    for (int m = 0; m < 4; m++) {
      const int idx = (wr * 64 + m * 16 + fr) * TK + slot8;
      ahs[m] = *(const f16x8*)&Ahs[idx];
      ah[m] = *(const f16x8*)&Ah[idx];
      al[m] = *(const f16x8*)&Al[idx];
    }
#pragma unroll
    for (int n = 0; n < 4; n++) {
      const int idx = (wc * 64 + n * 16 + fr) * TK + slot8;
      const f16x8 bhf = *(const f16x8*)&Bh[idx];
      const f16x8 blf = *(const f16x8*)&Bl[idx];
#pragma unroll
      for (int m = 0; m < 4; m++) {
        acc[m][n] = __builtin_amdgcn_mfma_f32_16x16x32_f16(ahs[m], bhf, acc[m][n], 0, 0, 0);
        acc[m][n] = __builtin_amdgcn_mfma_f32_16x16x32_f16(ah[m], blf, acc[m][n], 0, 0, 0);
        acc[m][n] = __builtin_amdgcn_mfma_f32_16x16x32_f16(al[m], bhf, acc[m][n], 0, 0, 0);
      }
    }
  }

  // C/D layout: col = lane&15, row = (lane>>4)*4 + reg (m89-verified)
  float* O = out + (size_t)bz * N * N;
  const float inv2048 = 1.0f / 2048.0f;
#pragma unroll
  for (int m = 0; m < 4; m++) {
#pragma unroll
    for (int r4 = 0; r4 < 4; r4++) {
      float* orow =
          &O[(size_t)(row0 + wr * 64 + m * 16 + g * 4 + r4) * N + col0 + wc * 64 + fr];
#pragma unroll
      for (int n = 0; n < 4; n++) orow[n * 16] = acc[m][n][r4] * inv2048;
    }
  }
}

// ---------------------------------------------------------------------------
// Kernel 2: per-row max, sum(exp), and softmax diagonal value.
// One 256-thread block per row (B*N = 16384 rows).
// ---------------------------------------------------------------------------
__global__ __launch_bounds__(256)
void row_stats(const float* __restrict__ scores, float* __restrict__ m_out,
               float* __restrict__ s_out, float* __restrict__ diag_out) {
  const int row = blockIdx.x;              // b*N + i
  const float* srow = scores + (size_t)row * N;
  const float4* r4 = (const float4*)srow;
  const int t = threadIdx.x;
  const int lane = t & 63, wid = t >> 6;
  float4 v0 = r4[t];
  float4 v1 = r4[t + 256];
  float mx = fmaxf(fmaxf(fmaxf(v0.x, v0.y), fmaxf(v0.z, v0.w)),
                   fmaxf(fmaxf(v1.x, v1.y), fmaxf(v1.z, v1.w)));
  __shared__ float redm[4], reds[4], bc[1];
#pragma unroll
  for (int o = 32; o > 0; o >>= 1) mx = fmaxf(mx, __shfl_down(mx, o));
  if (lane == 0) redm[wid] = mx;
  __syncthreads();
  if (t == 0) bc[0] = fmaxf(fmaxf(redm[0], redm[1]), fmaxf(redm[2], redm[3]));
  __syncthreads();
  const float m = bc[0];
  float s = expf(v0.x - m) + expf(v0.y - m) + expf(v0.z - m) + expf(v0.w - m)
          + expf(v1.x - m) + expf(v1.y - m) + expf(v1.z - m) + expf(v1.w - m);
#pragma unroll
  for (int o = 32; o > 0; o >>= 1) s += __shfl_down(s, o);
  if (lane == 0) reds[wid] = s;
  __syncthreads();
  if (t == 0) {
    float S = reds[0] + reds[1] + reds[2] + reds[3];
    int i = row & (N - 1);
    float sii = srow[i];
    m_out[row] = m;
    s_out[row] = S;
    diag_out[row] = expf(sii - m) / S;
  }
}

// ---------------------------------------------------------------------------
// Kernel 3: per-batch top-512 of diag (jax.lax.top_k tie-break: lower index
// first), then output the selected indices sorted ascending.
// One 1024-thread block per batch (1 compare-pair per thread per stage).
// ---------------------------------------------------------------------------
__global__ __launch_bounds__(1024)
void topk_inst(const float* __restrict__ diag, int* __restrict__ inst) {
  const int b = blockIdx.x;
  __shared__ float v[2048];
  __shared__ int id[2048];
  __shared__ int sel[K_INST];
  const int tid = threadIdx.x;
  for (int e = tid; e < 2048; e += 1024) { v[e] = diag[b * N + e]; id[e] = e; }
  __syncthreads();
  for (int k = 2; k <= 2048; k <<= 1) {
    for (int j = k >> 1; j > 0; j >>= 1) {
      const int p = tid;               // 1024 pairs, one per thread
      int i = 2 * p - (p & (j - 1));
      int ixj = i | j;
      float va = v[i], vb = v[ixj];
      int ia = id[i], ib = id[ixj];
      bool a_first = (va > vb) || (va == vb && ia < ib);  // descending order
      bool up = ((i & k) == 0);
      if (up != a_first) { v[i] = vb; v[ixj] = va; id[i] = ib; id[ixj] = ia; }
      __syncthreads();
    }
  }
  if (tid < K_INST) sel[tid] = id[tid];
  __syncthreads();
  // sort the 512 selected indices ascending (bitonic, 256 pairs)
  for (int k = 2; k <= K_INST; k <<= 1) {
    for (int j = k >> 1; j > 0; j >>= 1) {
      if (tid < 256) {
        int p = tid;
        int i = 2 * p - (p & (j - 1));
        int ixj = i | j;
        int a = sel[i], c = sel[ixj];
        bool a_first = a < c;           // ascending
        bool up = ((i & k) == 0);
        if (up != a_first) { sel[i] = c; sel[ixj] = a; }
      }
      __syncthreads();
    }
  }
  if (tid < K_INST) inst[b * K_INST + tid] = sel[tid];
}

// ---------------------------------------------------------------------------
// Kernel 4: rel row -> top-32 columns. KEY INSIGHT: within one row the
// softmax is strictly monotone in the raw score, so we sort raw scores —
// no expf, no m/S. Packed u64 keys (monotone f32 bits << 32 | (511-e))
// give single-compare bitonic stages with exact jax tie-break (lower e
// wins on equal value). Diagonal gets the max sentinel (ref masks to 1e9).
// One 256-thread block per rel row (B*512 = 4096 blocks).
// ---------------------------------------------------------------------------
__global__ __launch_bounds__(256)
void rel_topk(const float* __restrict__ scores, const int* __restrict__ inst,
              float* __restrict__ soi_out, int* __restrict__ pairs) {
  const int blk = blockIdx.x;
  const int b = blk >> 9;
  const int r = blk & 511;
  __shared__ unsigned long long kv[K_INST];
  __shared__ int selc[K_REL];
  __shared__ int sortedc[K_REL];
  const int tid = threadIdx.x;
  const int subj = inst[b * K_INST + r];
  const float* srow = scores + ((size_t)b * N + subj) * N;
  for (int e = tid; e < K_INST; e += 256) {
    unsigned int fb;
    if (e == r) {
      fb = 0xFFFFFFFFu;                         // 1e9 diagonal mask -> max key
    } else {
      const int col = inst[b * K_INST + e];
      unsigned int u = __float_as_uint(srow[col]);
      fb = (u >> 31) ? ~u : (u | 0x80000000u);  // total-order map for f32
    }
    kv[e] = ((unsigned long long)fb << 32) | (unsigned int)(K_INST - 1 - e);
  }
  __syncthreads();
  for (int k = 2; k <= K_INST; k <<= 1) {
    for (int j = k >> 1; j > 0; j >>= 1) {
      int p = tid;
      int i = 2 * p - (p & (j - 1));
      int ixj = i | j;
      unsigned long long a = kv[i], c = kv[ixj];
      bool up = ((i & k) == 0);
      // descending: a_first = (a > c); swap if up != a_first  <=>  up == (a < c)
      if (up == (a < c)) { kv[i] = c; kv[ixj] = a; }
      __syncthreads();
    }
  }
  if (tid < K_REL)
    selc[tid] = K_INST - 1 - (int)(kv[tid] & 0xFFFFFFFFu);
  __syncthreads();
  if (tid < K_REL) {
    int myc = selc[tid];
    int rank = 0;
#pragma unroll
    for (int p2 = 0; p2 < K_REL; p2++) rank += (selc[p2] < myc);
    sortedc[rank] = myc;
  }
  __syncthreads();
  if (tid < K_REL) {
    int cc = sortedc[tid];
    int obj = inst[b * K_INST + cc];
    size_t pidx = (size_t)b * PAIRS_PER_B + (size_t)r * K_REL + tid;
    soi_out[pidx * 3 + 0] = (float)b;
    soi_out[pidx * 3 + 1] = (float)subj;
    soi_out[pidx * 3 + 2] = (float)obj;
    pairs[pidx * 2 + 0] = subj;
    pairs[pidx * 2 + 1] = obj;
  }
}

// ---------------------------------------------------------------------------
// Kernel 5: rel_e = layernorm(q[subj] + q[obj]) over D=256, no affine.
// One wave per pair, float4 loads, pure shuffle reduce (no LDS, no barriers).
// 4 pairs per 256-thread block -> 32768 blocks.
// ---------------------------------------------------------------------------
__global__ __launch_bounds__(256)
void rel_embed(const float* __restrict__ q, const int* __restrict__ pairs,
               float* __restrict__ out) {
  const size_t p = (size_t)blockIdx.x * 4 + (threadIdx.x >> 6);
  const int lane = threadIdx.x & 63;
  const int b = (int)(p >> 14);
  const int subj = pairs[p * 2], obj = pairs[p * 2 + 1];
  const float* qs = q + ((size_t)b * N + subj) * D;
  const float* qo = q + ((size_t)b * N + obj) * D;
  const float4 a = *(const float4*)(qs + lane * 4);
  const float4 c = *(const float4*)(qo + lane * 4);
  float4 e = make_float4(a.x + c.x, a.y + c.y, a.z + c.z, a.w + c.w);
  float s = e.x + e.y + e.z + e.w;
#pragma unroll
  for (int o = 32; o > 0; o >>= 1) s += __shfl_down(s, o);
  const float mu = __shfl(s, 0) * (1.0f / D);
  float4 dv = make_float4(e.x - mu, e.y - mu, e.z - mu, e.w - mu);
  float s2 = dv.x * dv.x + dv.y * dv.y + dv.z * dv.z + dv.w * dv.w;
#pragma unroll
  for (int o = 32; o > 0; o >>= 1) s2 += __shfl_down(s2, o);
  const float var = __shfl(s2, 0) * (1.0f / D);
  const float r = rsqrtf(var + 1e-5f);
  *(float4*)(out + p * D + lane * 4) =
      make_float4(dv.x * r, dv.y * r, dv.z * r, dv.w * r);
}

// ---------------------------------------------------------------------------
extern "C" void kernel_launch(void* const* d_in, const int* in_sizes, int n_in,
                              void* d_out, int out_size, void* d_ws, size_t ws_size,
                              hipStream_t stream) {
  const float* q = (const float*)d_in[0];
  const float* k = (const float*)d_in[1];
  float* out = (float*)d_out;

  // Output layout (flat fp32, return order): scores1, soi, rel_e
  float* scores = out;                                   // 8*2048*2048
  float* soi = out + (size_t)BATCH * N * N;              // 8*16384*3
  float* rele = soi + (size_t)BATCH * PAIRS_PER_B * 3;   // 8*16384*256

  // Workspace layout
  float* m_arr = (float*)d_ws;                 // 16384 f
  float* s_arr = m_arr + BATCH * N;            // 16384 f
  float* diag = s_arr + BATCH * N;             // 16384 f
  int* inst = (int*)(diag + BATCH * N);        // 4096 i
  int* pairs = inst + BATCH * K_INST;          // 262144 i

  // fp16 stash (5 arrays, 42 MB) lives at the head of the rel_e output
  // region (134 MB). Consumed by the GEMM, fully overwritten by rel_embed
  // at the end; stream is serial so this is safe.
  unsigned short* qhs = (unsigned short*)rele;
  unsigned short* qh = qhs + (size_t)BATCH * N * D;
  unsigned short* ql = qh + (size_t)BATCH * N * D;
  unsigned short* kh = ql + (size_t)BATCH * N * D;
  unsigned short* kl = kh + (size_t)BATCH * N * D;

  split_f16<<<4096, 256, 0, stream>>>(q, k, qhs, qh, ql, kh, kl);
  gemm_qkT_mfma<<<dim3(N / TN, N / TM, BATCH), 256, 0, stream>>>(qhs, qh, ql, kh, kl, scores);
  row_stats<<<BATCH * N, 256, 0, stream>>>(scores, m_arr, s_arr, diag);
  topk_inst<<<BATCH, 1024, 0, stream>>>(diag, inst);
  rel_topk<<<BATCH * K_INST, 256, 0, stream>>>(scores, inst, soi, pairs);
  rel_embed<<<BATCH * PAIRS_PER_B / 4, 256, 0, stream>>>(q, pairs, rele);
}

// Round 6
// 420.500 us; speedup vs baseline: 1.5105x; 1.0010x over previous
//
#include <hip/hip_runtime.h>
#include <math.h>

#define BATCH 8
#define N 2048
#define D 256
#define K_INST 512
#define K_REL 32
#define PAIRS_PER_B (K_INST * K_REL)   // 16384

// ---------------------------------------------------------------------------
// fp32 -> fp16 hi/lo split (lo pre-scaled by 2^11 so it stays in fp16 normal
// range). x = h + l/2048 + r,  |r| <= 2^-24 |x|  (fp32-epsilon level).
// ---------------------------------------------------------------------------
__device__ __forceinline__ unsigned short f2h_u(float f) {
  _Float16 h = (_Float16)f;                       // RNE
  return __builtin_bit_cast(unsigned short, h);
}
__device__ __forceinline__ float h2f_u(unsigned short u) {
  return (float)__builtin_bit_cast(_Float16, u);  // exact
}

// Kernel 0: q,k fp32 -> qh/ql/kh/kl fp16 arrays (one pass, vectorized).
__global__ __launch_bounds__(256)
void split_f16(const float* __restrict__ q, const float* __restrict__ k,
               unsigned short* __restrict__ qh, unsigned short* __restrict__ ql,
               unsigned short* __restrict__ kh, unsigned short* __restrict__ kl) {
  const int E4 = BATCH * N * D / 4;   // float4 chunks per tensor
  for (int i = blockIdx.x * blockDim.x + threadIdx.x; i < 2 * E4;
       i += gridDim.x * blockDim.x) {
    const bool isK = i >= E4;
    const int j = isK ? (i - E4) : i;
    const float4 v = ((const float4*)(isK ? k : q))[j];
    ushort4 h, l;
    h.x = f2h_u(v.x); h.y = f2h_u(v.y); h.z = f2h_u(v.z); h.w = f2h_u(v.w);
    l.x = f2h_u(2048.0f * (v.x - h2f_u(h.x)));
    l.y = f2h_u(2048.0f * (v.y - h2f_u(h.y)));
    l.z = f2h_u(2048.0f * (v.z - h2f_u(h.z)));
    l.w = f2h_u(2048.0f * (v.w - h2f_u(h.w)));
    ((ushort4*)(isK ? kh : qh))[j] = h;
    ((ushort4*)(isK ? kl : ql))[j] = l;
  }
}

// ---------------------------------------------------------------------------
// Kernel 1: scores = q @ k^T via fp16-split MFMA, single acc bank at
// scale 2048:
//   acc' = mfma(2048*ah, bh) ; acc' = mfma(ah, bl) ; acc' = mfma(al, bh)
//   score = acc' * 2^-11
// 2048*ah computed IN REGISTERS (exact pow2 fp16 scale) — only 4 staged
// arrays (32 KiB LDS), 8 global_load_lds + 16 ds_read_b128 per wave/K-step.
// FUSED EPILOGUE: per-tile row max & sum(exp) partials for the softmax
// (kills the row_stats 134 MB re-read of scores).
// ---------------------------------------------------------------------------
#define TM 128
#define TN 128
#define TK 32

typedef _Float16 f16x8 __attribute__((ext_vector_type(8)));  // 8 f16 = 4 VGPRs
typedef float f32x4 __attribute__((ext_vector_type(4)));

__device__ __forceinline__ void load_lds16(const void* g, void* l) {
  __builtin_amdgcn_global_load_lds(
      (const __attribute__((address_space(1))) void*)g,
      (__attribute__((address_space(3))) void*)l, 16, 0, 0);
}

__global__ __launch_bounds__(256, 3)
void gemm_qkT_mfma(const unsigned short* __restrict__ qh,
                   const unsigned short* __restrict__ ql,
                   const unsigned short* __restrict__ kh,
                   const unsigned short* __restrict__ kl,
                   float* __restrict__ out,
                   float* __restrict__ pm, float* __restrict__ ps) {
  const int bz = blockIdx.z;
  const int row0 = blockIdx.y * TM;
  const int col0 = blockIdx.x * TN;
  const size_t tb = (size_t)bz * N * D;

  // 4 tiles of [128 rows][32 k] fp16, linear layout (32 KiB) + 4 KiB reduce.
  __shared__ unsigned short Ah[TM * TK], Al[TM * TK], Bh[TM * TK], Bl[TM * TK];
  __shared__ float redm[2][TM], reds[2][TM];

  const int tid = threadIdx.x;
  const int lane = tid & 63;
  const int w = tid >> 6;          // wave 0..3
  const int wr = w >> 1, wc = w & 1;
  const int fr = lane & 15;        // row/col within a 16x16 fragment
  const int g = lane >> 4;         // k-group 0..3 (8 f16 each)
  // XOR swizzle of the 16B k-chunk within a 64B row: chunk' = chunk ^ (row&3).
  const int slot8 = ((g ^ (lane & 3)) << 3);  // swizzled k-offset (ushorts)

  // staging decode: wave covers LDS bytes b = (2w+i)*1024 + lane*16 per tile
  int r_st[2], k_st[2];
#pragma unroll
  for (int i = 0; i < 2; i++) {
    const int b = ((w * 2 + i) << 10) + lane * 16;
    const int r = b >> 6;           // tile row 0..127
    const int s = (b >> 4) & 3;     // 16B slot within the row
    r_st[i] = r;
    k_st[i] = (s ^ (r & 3)) * 8;    // inverse-swizzled global k-chunk (ushorts)
  }

  f32x4 acc[4][4];
#pragma unroll
  for (int m = 0; m < 4; m++)
#pragma unroll
    for (int n = 0; n < 4; n++) acc[m][n] = (f32x4){0.f, 0.f, 0.f, 0.f};

  for (int kt = 0; kt < D; kt += TK) {
    __syncthreads();               // all waves done reading previous tile
#pragma unroll
    for (int i = 0; i < 2; i++) {
      const size_t aoff = tb + (size_t)(row0 + r_st[i]) * D + kt + k_st[i];
      const size_t boff = tb + (size_t)(col0 + r_st[i]) * D + kt + k_st[i];
      const int ldsoff = (w * 2 + i) * 512;        // wave-uniform dest
      load_lds16(qh + aoff, &Ah[ldsoff]);
      load_lds16(ql + aoff, &Al[ldsoff]);
      load_lds16(kh + boff, &Bh[ldsoff]);
      load_lds16(kl + boff, &Bl[ldsoff]);
    }
    __syncthreads();               // barrier drains vmcnt -> tiles ready

    f16x8 ahs[4], ah[4], al[4];
#pragma unroll
    for (int m = 0; m < 4; m++) {
      const int idx = (wr * 64 + m * 16 + fr) * TK + slot8;
      ah[m] = *(const f16x8*)&Ah[idx];
      al[m] = *(const f16x8*)&Al[idx];
      ahs[m] = ah[m] * (_Float16)2048.0f;   // exact pow2 scale, v_pk_mul_f16
    }
#pragma unroll
    for (int n = 0; n < 4; n++) {
      const int idx = (wc * 64 + n * 16 + fr) * TK + slot8;
      const f16x8 bhf = *(const f16x8*)&Bh[idx];
      const f16x8 blf = *(const f16x8*)&Bl[idx];
#pragma unroll
      for (int m = 0; m < 4; m++) {
        acc[m][n] = __builtin_amdgcn_mfma_f32_16x16x32_f16(ahs[m], bhf, acc[m][n], 0, 0, 0);
        acc[m][n] = __builtin_amdgcn_mfma_f32_16x16x32_f16(ah[m], blf, acc[m][n], 0, 0, 0);
        acc[m][n] = __builtin_amdgcn_mfma_f32_16x16x32_f16(al[m], bhf, acc[m][n], 0, 0, 0);
      }
    }
  }

  // Epilogue: store scores; fused per-tile row max / sum(exp) partials.
  // C/D layout: col = lane&15, row = (lane>>4)*4 + reg (m89-verified)
  float* O = out + (size_t)bz * N * N;
  const float inv2048 = 1.0f / 2048.0f;
#pragma unroll
  for (int m = 0; m < 4; m++) {
#pragma unroll
    for (int r4 = 0; r4 < 4; r4++) {
      float v0 = acc[m][0][r4] * inv2048;
      float v1 = acc[m][1][r4] * inv2048;
      float v2 = acc[m][2][r4] * inv2048;
      float v3 = acc[m][3][r4] * inv2048;
      float* orow =
          &O[(size_t)(row0 + wr * 64 + m * 16 + g * 4 + r4) * N + col0 + wc * 64 + fr];
      orow[0] = v0; orow[16] = v1; orow[32] = v2; orow[48] = v3;
      // row max over this wave's 64 cols (reduce across fr lanes)
      float mx = fmaxf(fmaxf(v0, v1), fmaxf(v2, v3));
#pragma unroll
      for (int o = 1; o < 16; o <<= 1) mx = fmaxf(mx, __shfl_xor(mx, o));
      float se = __expf(v0 - mx) + __expf(v1 - mx) + __expf(v2 - mx) + __expf(v3 - mx);
#pragma unroll
      for (int o = 1; o < 16; o <<= 1) se += __shfl_xor(se, o);
      if (fr == 0) {
        const int rrow = wr * 64 + m * 16 + g * 4 + r4;
        redm[wc][rrow] = mx;
        reds[wc][rrow] = se;
      }
    }
  }
  __syncthreads();
  if (tid < TM) {
    const float m0 = redm[0][tid], m1 = redm[1][tid];
    const float M = fmaxf(m0, m1);
    const float S = reds[0][tid] * __expf(m0 - M) + reds[1][tid] * __expf(m1 - M);
    const size_t idx = ((size_t)bz * N + row0 + tid) * 16 + blockIdx.x;
    pm[idx] = M;
    ps[idx] = S;
  }
}

// ---------------------------------------------------------------------------
// Kernel 2: combine 16 per-tile partials per row -> softmax diag value.
// One thread per row (16384 threads).
// ---------------------------------------------------------------------------
__global__ __launch_bounds__(256)
void row_combine(const float* __restrict__ pm, const float* __restrict__ ps,
                 const float* __restrict__ scores, float* __restrict__ diag) {
  const int row = blockIdx.x * 256 + threadIdx.x;   // b*N + i
  float pmv[16];
  float M = -INFINITY;
#pragma unroll
  for (int j = 0; j < 16; j++) {
    pmv[j] = pm[(size_t)row * 16 + j];
    M = fmaxf(M, pmv[j]);
  }
  float S = 0.f;
#pragma unroll
  for (int j = 0; j < 16; j++) S += ps[(size_t)row * 16 + j] * __expf(pmv[j] - M);
  const int i = row & (N - 1);
  const float sii = scores[(size_t)row * N + i];
  diag[row] = __expf(sii - M) / S;
}

// ---------------------------------------------------------------------------
// Kernel 3: per-batch top-512 of diag (jax.lax.top_k tie-break: lower index
// first), then output the selected indices sorted ascending.
// One 1024-thread block per batch (1 compare-pair per thread per stage).
// ---------------------------------------------------------------------------
__global__ __launch_bounds__(1024)
void topk_inst(const float* __restrict__ diag, int* __restrict__ inst) {
  const int b = blockIdx.x;
  __shared__ float v[2048];
  __shared__ int id[2048];
  __shared__ int sel[K_INST];
  const int tid = threadIdx.x;
  for (int e = tid; e < 2048; e += 1024) { v[e] = diag[b * N + e]; id[e] = e; }
  __syncthreads();
  for (int k = 2; k <= 2048; k <<= 1) {
    for (int j = k >> 1; j > 0; j >>= 1) {
      const int p = tid;               // 1024 pairs, one per thread
      int i = 2 * p - (p & (j - 1));
      int ixj = i | j;
      float va = v[i], vb = v[ixj];
      int ia = id[i], ib = id[ixj];
      bool a_first = (va > vb) || (va == vb && ia < ib);  // descending order
      bool up = ((i & k) == 0);
      if (up != a_first) { v[i] = vb; v[ixj] = va; id[i] = ib; id[ixj] = ia; }
      __syncthreads();
    }
  }
  if (tid < K_INST) sel[tid] = id[tid];
  __syncthreads();
  // sort the 512 selected indices ascending (bitonic, 256 pairs)
  for (int k = 2; k <= K_INST; k <<= 1) {
    for (int j = k >> 1; j > 0; j >>= 1) {
      if (tid < 256) {
        int p = tid;
        int i = 2 * p - (p & (j - 1));
        int ixj = i | j;
        int a = sel[i], c = sel[ixj];
        bool a_first = a < c;           // ascending
        bool up = ((i & k) == 0);
        if (up != a_first) { sel[i] = c; sel[ixj] = a; }
      }
      __syncthreads();
    }
  }
  if (tid < K_INST) inst[b * K_INST + tid] = sel[tid];
}

// ---------------------------------------------------------------------------
// Kernel 4: rel row -> top-32 columns. Softmax is strictly monotone in the
// raw score within a row, so sort raw scores (no expf). Packed u64 keys
// (monotone f32 bits << 32 | (511-e)) give single-compare bitonic stages
// with exact jax tie-break. Diagonal gets the max sentinel (ref masks 1e9).
// One 256-thread block per rel row (B*512 = 4096 blocks).
// ---------------------------------------------------------------------------
__global__ __launch_bounds__(256)
void rel_topk(const float* __restrict__ scores, const int* __restrict__ inst,
              float* __restrict__ soi_out, int* __restrict__ pairs) {
  const int blk = blockIdx.x;
  const int b = blk >> 9;
  const int r = blk & 511;
  __shared__ unsigned long long kv[K_INST];
  __shared__ int selc[K_REL];
  __shared__ int sortedc[K_REL];
  const int tid = threadIdx.x;
  const int subj = inst[b * K_INST + r];
  const float* srow = scores + ((size_t)b * N + subj) * N;
  for (int e = tid; e < K_INST; e += 256) {
    unsigned int fb;
    if (e == r) {
      fb = 0xFFFFFFFFu;                         // 1e9 diagonal mask -> max key
    } else {
      const int col = inst[b * K_INST + e];
      unsigned int u = __float_as_uint(srow[col]);
      fb = (u >> 31) ? ~u : (u | 0x80000000u);  // total-order map for f32
    }
    kv[e] = ((unsigned long long)fb << 32) | (unsigned int)(K_INST - 1 - e);
  }
  __syncthreads();
  for (int k = 2; k <= K_INST; k <<= 1) {
    for (int j = k >> 1; j > 0; j >>= 1) {
      int p = tid;
      int i = 2 * p - (p & (j - 1));
      int ixj = i | j;
      unsigned long long a = kv[i], c = kv[ixj];
      bool up = ((i & k) == 0);
      if (up == (a < c)) { kv[i] = c; kv[ixj] = a; }
      __syncthreads();
    }
  }
  if (tid < K_REL)
    selc[tid] = K_INST - 1 - (int)(kv[tid] & 0xFFFFFFFFu);
  __syncthreads();
  if (tid < K_REL) {
    int myc = selc[tid];
    int rank = 0;
#pragma unroll
    for (int p2 = 0; p2 < K_REL; p2++) rank += (selc[p2] < myc);
    sortedc[rank] = myc;
  }
  __syncthreads();
  if (tid < K_REL) {
    int cc = sortedc[tid];
    int obj = inst[b * K_INST + cc];
    size_t pidx = (size_t)b * PAIRS_PER_B + (size_t)r * K_REL + tid;
    soi_out[pidx * 3 + 0] = (float)b;
    soi_out[pidx * 3 + 1] = (float)subj;
    soi_out[pidx * 3 + 2] = (float)obj;
    pairs[pidx * 2 + 0] = subj;
    pairs[pidx * 2 + 1] = obj;
  }
}

// ---------------------------------------------------------------------------
// Kernel 5: rel_e = layernorm(q[subj] + q[obj]) over D=256, no affine.
// One wave per pair, float4 loads, pure shuffle reduce (no LDS, no barriers).
// 4 pairs per 256-thread block -> 32768 blocks.
// ---------------------------------------------------------------------------
__global__ __launch_bounds__(256)
void rel_embed(const float* __restrict__ q, const int* __restrict__ pairs,
               float* __restrict__ out) {
  const size_t p = (size_t)blockIdx.x * 4 + (threadIdx.x >> 6);
  const int lane = threadIdx.x & 63;
  const int b = (int)(p >> 14);
  const int subj = pairs[p * 2], obj = pairs[p * 2 + 1];
  const float* qs = q + ((size_t)b * N + subj) * D;
  const float* qo = q + ((size_t)b * N + obj) * D;
  const float4 a = *(const float4*)(qs + lane * 4);
  const float4 c = *(const float4*)(qo + lane * 4);
  float4 e = make_float4(a.x + c.x, a.y + c.y, a.z + c.z, a.w + c.w);
  float s = e.x + e.y + e.z + e.w;
#pragma unroll
  for (int o = 32; o > 0; o >>= 1) s += __shfl_down(s, o);
  const float mu = __shfl(s, 0) * (1.0f / D);
  float4 dv = make_float4(e.x - mu, e.y - mu, e.z - mu, e.w - mu);
  float s2 = dv.x * dv.x + dv.y * dv.y + dv.z * dv.z + dv.w * dv.w;
#pragma unroll
  for (int o = 32; o > 0; o >>= 1) s2 += __shfl_down(s2, o);
  const float var = __shfl(s2, 0) * (1.0f / D);
  const float r = rsqrtf(var + 1e-5f);
  *(float4*)(out + p * D + lane * 4) =
      make_float4(dv.x * r, dv.y * r, dv.z * r, dv.w * r);
}

// ---------------------------------------------------------------------------
extern "C" void kernel_launch(void* const* d_in, const int* in_sizes, int n_in,
                              void* d_out, int out_size, void* d_ws, size_t ws_size,
                              hipStream_t stream) {
  const float* q = (const float*)d_in[0];
  const float* k = (const float*)d_in[1];
  float* out = (float*)d_out;

  // Output layout (flat fp32, return order): scores1, soi, rel_e
  float* scores = out;                                   // 8*2048*2048
  float* soi = out + (size_t)BATCH * N * N;              // 8*16384*3
  float* rele = soi + (size_t)BATCH * PAIRS_PER_B * 3;   // 8*16384*256

  // Workspace layout
  float* diag = (float*)d_ws;                  // 16384 f
  int* inst = (int*)(diag + BATCH * N);        // 4096 i
  int* pairs = inst + BATCH * K_INST;          // 262144 i

  // fp16 stash (4 arrays, 32 MB) + softmax partials (2 MB) live at the head
  // of the rel_e output region (134 MB). Consumed before rel_embed
  // overwrites the region at the end; stream is serial so this is safe.
  unsigned short* qh = (unsigned short*)rele;
  unsigned short* ql = qh + (size_t)BATCH * N * D;
  unsigned short* kh = ql + (size_t)BATCH * N * D;
  unsigned short* kl = kh + (size_t)BATCH * N * D;
  float* pm = (float*)(kl + (size_t)BATCH * N * D);   // [B*N][16]
  float* ps = pm + (size_t)BATCH * N * 16;            // [B*N][16]

  split_f16<<<4096, 256, 0, stream>>>(q, k, qh, ql, kh, kl);
  gemm_qkT_mfma<<<dim3(N / TN, N / TM, BATCH), 256, 0, stream>>>(qh, ql, kh, kl, scores, pm, ps);
  row_combine<<<BATCH * N / 256, 256, 0, stream>>>(pm, ps, scores, diag);
  topk_inst<<<BATCH, 1024, 0, stream>>>(diag, inst);
  rel_topk<<<BATCH * K_INST, 256, 0, stream>>>(scores, inst, soi, pairs);
  rel_embed<<<BATCH * PAIRS_PER_B / 4, 256, 0, stream>>>(q, pairs, rele);
}

// Round 7
// 416.910 us; speedup vs baseline: 1.5235x; 1.0086x over previous
//
#include <hip/hip_runtime.h>
#include <math.h>

#define BATCH 8
#define N 2048
#define D 256
#define K_INST 512
#define K_REL 32
#define PAIRS_PER_B (K_INST * K_REL)   // 16384

// ---------------------------------------------------------------------------
// fp32 -> fp16 hi/lo split (lo pre-scaled by 2^11 so it stays in fp16 normal
// range). x = h + l/2048 + r,  |r| <= 2^-24 |x|  (fp32-epsilon level).
// ---------------------------------------------------------------------------
__device__ __forceinline__ unsigned short f2h_u(float f) {
  _Float16 h = (_Float16)f;                       // RNE
  return __builtin_bit_cast(unsigned short, h);
}
__device__ __forceinline__ float h2f_u(unsigned short u) {
  return (float)__builtin_bit_cast(_Float16, u);  // exact
}

// Kernel 0: q,k fp32 -> qh/ql/kh/kl fp16 arrays (one pass, vectorized).
__global__ __launch_bounds__(256)
void split_f16(const float* __restrict__ q, const float* __restrict__ k,
               unsigned short* __restrict__ qh, unsigned short* __restrict__ ql,
               unsigned short* __restrict__ kh, unsigned short* __restrict__ kl) {
  const int E4 = BATCH * N * D / 4;   // float4 chunks per tensor
  for (int i = blockIdx.x * blockDim.x + threadIdx.x; i < 2 * E4;
       i += gridDim.x * blockDim.x) {
    const bool isK = i >= E4;
    const int j = isK ? (i - E4) : i;
    const float4 v = ((const float4*)(isK ? k : q))[j];
    ushort4 h, l;
    h.x = f2h_u(v.x); h.y = f2h_u(v.y); h.z = f2h_u(v.z); h.w = f2h_u(v.w);
    l.x = f2h_u(2048.0f * (v.x - h2f_u(h.x)));
    l.y = f2h_u(2048.0f * (v.y - h2f_u(h.y)));
    l.z = f2h_u(2048.0f * (v.z - h2f_u(h.z)));
    l.w = f2h_u(2048.0f * (v.w - h2f_u(h.w)));
    ((ushort4*)(isK ? kh : qh))[j] = h;
    ((ushort4*)(isK ? kl : ql))[j] = l;
  }
}

// ---------------------------------------------------------------------------
// Kernel 1: scores = q @ k^T via fp16-split MFMA, single acc bank at
// scale 2048:
//   acc' = mfma(2048*ah, bh) ; acc' = mfma(ah, bl) ; acc' = mfma(al, bh)
//   score = acc' * 2^-11
// LDS swizzle v2: chunk' = chunk ^ ((row>>1)&3). Bank math: for a 16-lane
// fragment group, bank_start(fr) = 4*((4*fr + (fr>>1)&3) mod 8) covers each
// bank-quad exactly twice -> 2-way aliasing (free, m136) instead of the
// previous (row&3) XOR's 4-way (1.58x). Both-sides rule: staging source
// uses the same involution.
// FUSED EPILOGUE: per-tile row max & sum(exp) partials for the softmax.
// ---------------------------------------------------------------------------
#define TM 128
#define TN 128
#define TK 32

typedef _Float16 f16x8 __attribute__((ext_vector_type(8)));  // 8 f16 = 4 VGPRs
typedef float f32x4 __attribute__((ext_vector_type(4)));

__device__ __forceinline__ void load_lds16(const void* g, void* l) {
  __builtin_amdgcn_global_load_lds(
      (const __attribute__((address_space(1))) void*)g,
      (__attribute__((address_space(3))) void*)l, 16, 0, 0);
}

__global__ __launch_bounds__(256, 3)
void gemm_qkT_mfma(const unsigned short* __restrict__ qh,
                   const unsigned short* __restrict__ ql,
                   const unsigned short* __restrict__ kh,
                   const unsigned short* __restrict__ kl,
                   float* __restrict__ out,
                   float* __restrict__ pm, float* __restrict__ ps) {
  const int bz = blockIdx.z;
  const int row0 = blockIdx.y * TM;
  const int col0 = blockIdx.x * TN;
  const size_t tb = (size_t)bz * N * D;

  // 4 tiles of [128 rows][32 k] fp16, linear layout (32 KiB) + 4 KiB reduce.
  __shared__ unsigned short Ah[TM * TK], Al[TM * TK], Bh[TM * TK], Bl[TM * TK];
  __shared__ float redm[2][TM], reds[2][TM];

  const int tid = threadIdx.x;
  const int lane = tid & 63;
  const int w = tid >> 6;          // wave 0..3
  const int wr = w >> 1, wc = w & 1;
  const int fr = lane & 15;        // row/col within a 16x16 fragment
  const int g = lane >> 4;         // k-group 0..3 (8 f16 each)
  // v2 swizzle: chunk' = g ^ ((fr>>1)&3). (lane>>1)&3 == (fr>>1)&3 since
  // lane = 16g + fr and 8g mod 4 == 0. Fragment bases are multiples of 16,
  // so (row>>1)&3 == (fr>>1)&3 for every fragment row.
  const int slot8 = ((g ^ ((lane >> 1) & 3)) << 3);  // swizzled k-off (ushorts)

  // staging decode: wave covers LDS bytes b = (2w+i)*1024 + lane*16 per tile
  int r_st[2], k_st[2];
#pragma unroll
  for (int i = 0; i < 2; i++) {
    const int b = ((w * 2 + i) << 10) + lane * 16;
    const int r = b >> 6;           // tile row 0..127
    const int s = (b >> 4) & 3;     // 16B slot within the row
    r_st[i] = r;
    k_st[i] = (s ^ ((r >> 1) & 3)) * 8;  // inverse-swizzled global k-chunk
  }

  f32x4 acc[4][4];
#pragma unroll
  for (int m = 0; m < 4; m++)
#pragma unroll
    for (int n = 0; n < 4; n++) acc[m][n] = (f32x4){0.f, 0.f, 0.f, 0.f};

  for (int kt = 0; kt < D; kt += TK) {
    __syncthreads();               // all waves done reading previous tile
#pragma unroll
    for (int i = 0; i < 2; i++) {
      const size_t aoff = tb + (size_t)(row0 + r_st[i]) * D + kt + k_st[i];
      const size_t boff = tb + (size_t)(col0 + r_st[i]) * D + kt + k_st[i];
      const int ldsoff = (w * 2 + i) * 512;        // wave-uniform dest
      load_lds16(qh + aoff, &Ah[ldsoff]);
      load_lds16(ql + aoff, &Al[ldsoff]);
      load_lds16(kh + boff, &Bh[ldsoff]);
      load_lds16(kl + boff, &Bl[ldsoff]);
    }
    __syncthreads();               // barrier drains vmcnt -> tiles ready

    f16x8 ahs[4], ah[4], al[4];
#pragma unroll
    for (int m = 0; m < 4; m++) {
      const int idx = (wr * 64 + m * 16 + fr) * TK + slot8;
      ah[m] = *(const f16x8*)&Ah[idx];
      al[m] = *(const f16x8*)&Al[idx];
      ahs[m] = ah[m] * (_Float16)2048.0f;   // exact pow2 scale, v_pk_mul_f16
    }
#pragma unroll
    for (int n = 0; n < 4; n++) {
      const int idx = (wc * 64 + n * 16 + fr) * TK + slot8;
      const f16x8 bhf = *(const f16x8*)&Bh[idx];
      const f16x8 blf = *(const f16x8*)&Bl[idx];
#pragma unroll
      for (int m = 0; m < 4; m++) {
        acc[m][n] = __builtin_amdgcn_mfma_f32_16x16x32_f16(ahs[m], bhf, acc[m][n], 0, 0, 0);
        acc[m][n] = __builtin_amdgcn_mfma_f32_16x16x32_f16(ah[m], blf, acc[m][n], 0, 0, 0);
        acc[m][n] = __builtin_amdgcn_mfma_f32_16x16x32_f16(al[m], bhf, acc[m][n], 0, 0, 0);
      }
    }
  }

  // Epilogue: store scores; fused per-tile row max / sum(exp) partials.
  // C/D layout: col = lane&15, row = (lane>>4)*4 + reg (m89-verified)
  float* O = out + (size_t)bz * N * N;
  const float inv2048 = 1.0f / 2048.0f;
#pragma unroll
  for (int m = 0; m < 4; m++) {
#pragma unroll
    for (int r4 = 0; r4 < 4; r4++) {
      float v0 = acc[m][0][r4] * inv2048;
      float v1 = acc[m][1][r4] * inv2048;
      float v2 = acc[m][2][r4] * inv2048;
      float v3 = acc[m][3][r4] * inv2048;
      float* orow =
          &O[(size_t)(row0 + wr * 64 + m * 16 + g * 4 + r4) * N + col0 + wc * 64 + fr];
      orow[0] = v0; orow[16] = v1; orow[32] = v2; orow[48] = v3;
      // row max over this wave's 64 cols (reduce across fr lanes)
      float mx = fmaxf(fmaxf(v0, v1), fmaxf(v2, v3));
#pragma unroll
      for (int o = 1; o < 16; o <<= 1) mx = fmaxf(mx, __shfl_xor(mx, o));
      float se = __expf(v0 - mx) + __expf(v1 - mx) + __expf(v2 - mx) + __expf(v3 - mx);
#pragma unroll
      for (int o = 1; o < 16; o <<= 1) se += __shfl_xor(se, o);
      if (fr == 0) {
        const int rrow = wr * 64 + m * 16 + g * 4 + r4;
        redm[wc][rrow] = mx;
        reds[wc][rrow] = se;
      }
    }
  }
  __syncthreads();
  if (tid < TM) {
    const float m0 = redm[0][tid], m1 = redm[1][tid];
    const float M = fmaxf(m0, m1);
    const float S = reds[0][tid] * __expf(m0 - M) + reds[1][tid] * __expf(m1 - M);
    const size_t idx = ((size_t)bz * N + row0 + tid) * 16 + blockIdx.x;
    pm[idx] = M;
    ps[idx] = S;
  }
}

// ---------------------------------------------------------------------------
// Kernel 2: combine 16 per-tile partials per row -> softmax diag value.
// One thread per row (16384 threads).
// ---------------------------------------------------------------------------
__global__ __launch_bounds__(256)
void row_combine(const float* __restrict__ pm, const float* __restrict__ ps,
                 const float* __restrict__ scores, float* __restrict__ diag) {
  const int row = blockIdx.x * 256 + threadIdx.x;   // b*N + i
  float pmv[16];
  float M = -INFINITY;
#pragma unroll
  for (int j = 0; j < 16; j++) {
    pmv[j] = pm[(size_t)row * 16 + j];
    M = fmaxf(M, pmv[j]);
  }
  float S = 0.f;
#pragma unroll
  for (int j = 0; j < 16; j++) S += ps[(size_t)row * 16 + j] * __expf(pmv[j] - M);
  const int i = row & (N - 1);
  const float sii = scores[(size_t)row * N + i];
  diag[row] = __expf(sii - M) / S;
}

// ---------------------------------------------------------------------------
// Kernel 3: per-batch top-512 of diag (jax.lax.top_k tie-break: lower index
// first), then output the selected indices sorted ascending.
// One 1024-thread block per batch (1 compare-pair per thread per stage).
// ---------------------------------------------------------------------------
__global__ __launch_bounds__(1024)
void topk_inst(const float* __restrict__ diag, int* __restrict__ inst) {
  const int b = blockIdx.x;
  __shared__ float v[2048];
  __shared__ int id[2048];
  __shared__ int sel[K_INST];
  const int tid = threadIdx.x;
  for (int e = tid; e < 2048; e += 1024) { v[e] = diag[b * N + e]; id[e] = e; }
  __syncthreads();
  for (int k = 2; k <= 2048; k <<= 1) {
    for (int j = k >> 1; j > 0; j >>= 1) {
      const int p = tid;               // 1024 pairs, one per thread
      int i = 2 * p - (p & (j - 1));
      int ixj = i | j;
      float va = v[i], vb = v[ixj];
      int ia = id[i], ib = id[ixj];
      bool a_first = (va > vb) || (va == vb && ia < ib);  // descending order
      bool up = ((i & k) == 0);
      if (up != a_first) { v[i] = vb; v[ixj] = va; id[i] = ib; id[ixj] = ia; }
      __syncthreads();
    }
  }
  if (tid < K_INST) sel[tid] = id[tid];
  __syncthreads();
  // sort the 512 selected indices ascending (bitonic, 256 pairs)
  for (int k = 2; k <= K_INST; k <<= 1) {
    for (int j = k >> 1; j > 0; j >>= 1) {
      if (tid < 256) {
        int p = tid;
        int i = 2 * p - (p & (j - 1));
        int ixj = i | j;
        int a = sel[i], c = sel[ixj];
        bool a_first = a < c;           // ascending
        bool up = ((i & k) == 0);
        if (up != a_first) { sel[i] = c; sel[ixj] = a; }
      }
      __syncthreads();
    }
  }
  if (tid < K_INST) inst[b * K_INST + tid] = sel[tid];
}

// ---------------------------------------------------------------------------
// Kernel 4: rel row -> top-32 columns. Softmax is strictly monotone in the
// raw score within a row, so sort raw scores (no expf). Packed u64 keys
// (monotone f32 bits << 32 | (511-e)) give single-compare bitonic stages
// with exact jax tie-break. Diagonal gets the max sentinel (ref masks 1e9).
// One 256-thread block per rel row (B*512 = 4096 blocks).
// ---------------------------------------------------------------------------
__global__ __launch_bounds__(256)
void rel_topk(const float* __restrict__ scores, const int* __restrict__ inst,
              float* __restrict__ soi_out, int* __restrict__ pairs) {
  const int blk = blockIdx.x;
  const int b = blk >> 9;
  const int r = blk & 511;
  __shared__ unsigned long long kv[K_INST];
  __shared__ int selc[K_REL];
  __shared__ int sortedc[K_REL];
  const int tid = threadIdx.x;
  const int subj = inst[b * K_INST + r];
  const float* srow = scores + ((size_t)b * N + subj) * N;
  for (int e = tid; e < K_INST; e += 256) {
    unsigned int fb;
    if (e == r) {
      fb = 0xFFFFFFFFu;                         // 1e9 diagonal mask -> max key
    } else {
      const int col = inst[b * K_INST + e];
      unsigned int u = __float_as_uint(srow[col]);
      fb = (u >> 31) ? ~u : (u | 0x80000000u);  // total-order map for f32
    }
    kv[e] = ((unsigned long long)fb << 32) | (unsigned int)(K_INST - 1 - e);
  }
  __syncthreads();
  for (int k = 2; k <= K_INST; k <<= 1) {
    for (int j = k >> 1; j > 0; j >>= 1) {
      int p = tid;
      int i = 2 * p - (p & (j - 1));
      int ixj = i | j;
      unsigned long long a = kv[i], c = kv[ixj];
      bool up = ((i & k) == 0);
      if (up == (a < c)) { kv[i] = c; kv[ixj] = a; }
      __syncthreads();
    }
  }
  if (tid < K_REL)
    selc[tid] = K_INST - 1 - (int)(kv[tid] & 0xFFFFFFFFu);
  __syncthreads();
  if (tid < K_REL) {
    int myc = selc[tid];
    int rank = 0;
#pragma unroll
    for (int p2 = 0; p2 < K_REL; p2++) rank += (selc[p2] < myc);
    sortedc[rank] = myc;
  }
  __syncthreads();
  if (tid < K_REL) {
    int cc = sortedc[tid];
    int obj = inst[b * K_INST + cc];
    size_t pidx = (size_t)b * PAIRS_PER_B + (size_t)r * K_REL + tid;
    soi_out[pidx * 3 + 0] = (float)b;
    soi_out[pidx * 3 + 1] = (float)subj;
    soi_out[pidx * 3 + 2] = (float)obj;
    pairs[pidx * 2 + 0] = subj;
    pairs[pidx * 2 + 1] = obj;
  }
}

// ---------------------------------------------------------------------------
// Kernel 5: rel_e = layernorm(q[subj] + q[obj]) over D=256, no affine.
// One wave per pair, float4 loads, pure shuffle reduce (no LDS, no barriers).
// 4 pairs per 256-thread block -> 32768 blocks.
// ---------------------------------------------------------------------------
__global__ __launch_bounds__(256)
void rel_embed(const float* __restrict__ q, const int* __restrict__ pairs,
               float* __restrict__ out) {
  const size_t p = (size_t)blockIdx.x * 4 + (threadIdx.x >> 6);
  const int lane = threadIdx.x & 63;
  const int b = (int)(p >> 14);
  const int subj = pairs[p * 2], obj = pairs[p * 2 + 1];
  const float* qs = q + ((size_t)b * N + subj) * D;
  const float* qo = q + ((size_t)b * N + obj) * D;
  const float4 a = *(const float4*)(qs + lane * 4);
  const float4 c = *(const float4*)(qo + lane * 4);
  float4 e = make_float4(a.x + c.x, a.y + c.y, a.z + c.z, a.w + c.w);
  float s = e.x + e.y + e.z + e.w;
#pragma unroll
  for (int o = 32; o > 0; o >>= 1) s += __shfl_down(s, o);
  const float mu = __shfl(s, 0) * (1.0f / D);
  float4 dv = make_float4(e.x - mu, e.y - mu, e.z - mu, e.w - mu);
  float s2 = dv.x * dv.x + dv.y * dv.y + dv.z * dv.z + dv.w * dv.w;
#pragma unroll
  for (int o = 32; o > 0; o >>= 1) s2 += __shfl_down(s2, o);
  const float var = __shfl(s2, 0) * (1.0f / D);
  const float r = rsqrtf(var + 1e-5f);
  *(float4*)(out + p * D + lane * 4) =
      make_float4(dv.x * r, dv.y * r, dv.z * r, dv.w * r);
}

// ---------------------------------------------------------------------------
extern "C" void kernel_launch(void* const* d_in, const int* in_sizes, int n_in,
                              void* d_out, int out_size, void* d_ws, size_t ws_size,
                              hipStream_t stream) {
  const float* q = (const float*)d_in[0];
  const float* k = (const float*)d_in[1];
  float* out = (float*)d_out;

  // Output layout (flat fp32, return order): scores1, soi, rel_e
  float* scores = out;                                   // 8*2048*2048
  float* soi = out + (size_t)BATCH * N * N;              // 8*16384*3
  float* rele = soi + (size_t)BATCH * PAIRS_PER_B * 3;   // 8*16384*256

  // Workspace layout
  float* diag = (float*)d_ws;                  // 16384 f
  int* inst = (int*)(diag + BATCH * N);        // 4096 i
  int* pairs = inst + BATCH * K_INST;          // 262144 i

  // fp16 stash (4 arrays, 32 MB) + softmax partials (2 MB) live at the head
  // of the rel_e output region (134 MB). Consumed before rel_embed
  // overwrites the region at the end; stream is serial so this is safe.
  unsigned short* qh = (unsigned short*)rele;
  unsigned short* ql = qh + (size_t)BATCH * N * D;
  unsigned short* kh = ql + (size_t)BATCH * N * D;
  unsigned short* kl = kh + (size_t)BATCH * N * D;
  float* pm = (float*)(kl + (size_t)BATCH * N * D);   // [B*N][16]
  float* ps = pm + (size_t)BATCH * N * 16;            // [B*N][16]

  split_f16<<<4096, 256, 0, stream>>>(q, k, qh, ql, kh, kl);
  gemm_qkT_mfma<<<dim3(N / TN, N / TM, BATCH), 256, 0, stream>>>(qh, ql, kh, kl, scores, pm, ps);
  row_combine<<<BATCH * N / 256, 256, 0, stream>>>(pm, ps, scores, diag);
  topk_inst<<<BATCH, 1024, 0, stream>>>(diag, inst);
  rel_topk<<<BATCH * K_INST, 256, 0, stream>>>(scores, inst, soi, pairs);
  rel_embed<<<BATCH * PAIRS_PER_B / 4, 256, 0, stream>>>(q, pairs, rele);
}